// Round 2
// baseline (1182.905 us; speedup 1.0000x reference)
//
#include <hip/hip_runtime.h>
#include <hip/hip_bf16.h>

typedef __attribute__((ext_vector_type(8))) short bf16x8;
typedef __attribute__((ext_vector_type(4))) float f32x4;

__device__ __forceinline__ void async16(const void* g, void* l) {
    __builtin_amdgcn_global_load_lds(
        (const __attribute__((address_space(1))) void*)g,
        (__attribute__((address_space(3))) void*)l,
        16, 0, 0);
}

__device__ __forceinline__ unsigned short f2bf(float f) {
    __hip_bfloat16 h = __float2bfloat16(f);
    union { __hip_bfloat16 h; unsigned short u; } cv;
    cv.h = h;
    return cv.u;
}

// 8 rows of x per block. V chunk (1024 rows x 8) staged into LDS transposed
// ([8][1024]) with coalesced global reads; compute reads are conflict-free
// ds_read_b128. h[row][0:8] = 2*codes*(x@V); also writes bf16 x.
#define PREP_ROWS 8
__global__ __launch_bounds__(256) void prep_x(
    const float* __restrict__ x, const float* __restrict__ codes,
    const float* __restrict__ V, unsigned short* __restrict__ xb,
    float* __restrict__ h, int K) {
    __shared__ float Vs[8][1024];   // 32 KB, transposed chunk of V
    const int row0 = blockIdx.x * PREP_ROWS;
    const int t = threadIdx.x;
    const int lane = t & 63, wave = t >> 6;

    float acc[PREP_ROWS][8];
    #pragma unroll
    for (int row = 0; row < PREP_ROWS; ++row)
        #pragma unroll
        for (int r = 0; r < 8; ++r) acc[row][r] = 0.f;

    for (int it = 0; it < 4; ++it) {
        const int dbase = it * 1024;
        __syncthreads();   // protect previous chunk's reads
        // stage V[dbase..dbase+1023][0:8] transposed: 2048 float4, coalesced
        #pragma unroll
        for (int q = 0; q < 8; ++q) {
            int idx = q * 256 + t;            // float4 index in chunk
            float4 v = ((const float4*)(V + (size_t)dbase * 8))[idx];
            int d = idx >> 1, rh = (idx & 1) * 4;
            Vs[rh + 0][d] = v.x; Vs[rh + 1][d] = v.y;
            Vs[rh + 2][d] = v.z; Vs[rh + 3][d] = v.w;
        }
        __syncthreads();

        const int dl = t * 4;                 // local d of this thread's 4 cols
        float4 vr[8];
        #pragma unroll
        for (int r = 0; r < 8; ++r) vr[r] = *(const float4*)&Vs[r][dl];

        #pragma unroll
        for (int row = 0; row < PREP_ROWS; ++row) {
            const size_t base = (size_t)(row0 + row) * K + dbase + dl;
            float4 xv = *(const float4*)(x + base);
            ushort4 pk;
            pk.x = f2bf(xv.x); pk.y = f2bf(xv.y);
            pk.z = f2bf(xv.z); pk.w = f2bf(xv.w);
            *(ushort4*)(xb + base) = pk;
            float vx[4] = {xv.x, xv.y, xv.z, xv.w};
            #pragma unroll
            for (int q = 0; q < 4; ++q) {
                acc[row][0] += vx[q] * ((const float*)&vr[0])[q];
                acc[row][1] += vx[q] * ((const float*)&vr[1])[q];
                acc[row][2] += vx[q] * ((const float*)&vr[2])[q];
                acc[row][3] += vx[q] * ((const float*)&vr[3])[q];
                acc[row][4] += vx[q] * ((const float*)&vr[4])[q];
                acc[row][5] += vx[q] * ((const float*)&vr[5])[q];
                acc[row][6] += vx[q] * ((const float*)&vr[6])[q];
                acc[row][7] += vx[q] * ((const float*)&vr[7])[q];
            }
        }
    }

    // wave reduce (64 lanes) per (row, r)
    #pragma unroll
    for (int row = 0; row < PREP_ROWS; ++row)
        #pragma unroll
        for (int r = 0; r < 8; ++r) {
            float a = acc[row][r];
            #pragma unroll
            for (int off = 32; off > 0; off >>= 1)
                a += __shfl_down(a, off);
            acc[row][r] = a;
        }

    __shared__ float red[4][PREP_ROWS][8];
    __syncthreads();
    if (lane == 0)
        #pragma unroll
        for (int row = 0; row < PREP_ROWS; ++row)
            #pragma unroll
            for (int r = 0; r < 8; ++r) red[wave][row][r] = acc[row][r];
    __syncthreads();
    if (t < PREP_ROWS * 8) {
        const int row = t >> 3, r = t & 7;
        float s = red[0][row][r] + red[1][row][r] + red[2][row][r] + red[3][row][r];
        const size_t gi = (size_t)(row0 + row) * 8 + r;
        h[gi] = 2.0f * codes[gi] * s;
    }
}

__global__ __launch_bounds__(256) void cast_w(
    const float* __restrict__ W, unsigned short* __restrict__ Wb, long n4) {
    long i = (long)blockIdx.x * 256 + threadIdx.x;
    if (i < n4) {
        float4 w = ((const float4*)W)[i];
        ushort4 pk;
        pk.x = f2bf(w.x); pk.y = f2bf(w.y); pk.z = f2bf(w.z); pk.w = f2bf(w.w);
        ((ushort4*)Wb)[i] = pk;
    }
}

// C[m,n] = dot(A[m,:], B[n,:]) + bias[n] + dot8(h[m,:], U[n,:])
// 256x256 tile, BK=32, 8 waves (2M x 4N), 4 LDS slots, counted vmcnt
// (never drains to 0 in main loop), XOR-swizzled LDS (16B slot ^= (row>>1)&3)
// applied on pre-swizzled global source + swizzled ds_read (both-sides rule).
#define BM 256
#define BN 256
#define BK 32
__global__ __launch_bounds__(512, 2) void gemm_bt(
    const unsigned short* __restrict__ A, const unsigned short* __restrict__ B,
    const float* __restrict__ bias, const float* __restrict__ h,
    const float* __restrict__ U, float* __restrict__ C,
    int M, int N, int K) {
    __shared__ unsigned short As[4][BM * BK];   // 4 x 16 KB
    __shared__ unsigned short Bs[4][BN * BK];   // 4 x 16 KB  (total 128 KB)

    const int t = threadIdx.x;                  // 0..511
    const int lane = t & 63, wave = t >> 6;     // 8 waves
    const int wm = wave >> 2, wn = wave & 3;    // 2M x 4N
    const int quad = lane >> 4, l16 = lane & 15;
    const int m0 = blockIdx.y * BM, n0 = blockIdx.x * BN;
    const int NT = K / BK;                      // 128

    f32x4 acc[8][4] = {};

    // stage K-tile kt_ into slot kt_&3. 4 async16/thread (2 A + 2 B).
    // linear LDS dest (idx*16B); source slot pre-swizzled so that a read at
    // [row][slot ^ ((row>>1)&3)] returns logical [row][slot].
    auto stage = [&](int kt_) {
        const int kbase = kt_ * BK;
        const int slot = kt_ & 3;
        #pragma unroll
        for (int q = 0; q < 2; ++q) {
            int idx = q * 512 + t;
            int r = idx >> 2;
            int ls = (t & 3) ^ ((r >> 1) & 3);
            async16(A + (size_t)(m0 + r) * K + kbase + ls * 8,
                    &As[slot][(size_t)idx * 8]);
        }
        #pragma unroll
        for (int q = 0; q < 2; ++q) {
            int idx = q * 512 + t;
            int r = idx >> 2;
            int ls = (t & 3) ^ ((r >> 1) & 3);
            async16(B + (size_t)(n0 + r) * K + kbase + ls * 8,
                    &Bs[slot][(size_t)idx * 8]);
        }
    };

    // prologue: 3 tiles in flight; wait tile 0 (8 = 2 tiles x 4 loads remain)
    stage(0); stage(1); stage(2);
    asm volatile("s_waitcnt vmcnt(8)" ::: "memory");
    __builtin_amdgcn_sched_barrier(0);
    __builtin_amdgcn_s_barrier();

    const int swz = (quad ^ ((l16 >> 1) & 3)) * 8;   // swizzled 16B slot

    for (int kt = 0; kt < NT; ++kt) {
        const int slot = kt & 3;
        if (kt + 3 < NT) stage(kt + 3);   // overwrites slot of kt-1 (dead)

        const unsigned short* Ab = As[slot];
        const unsigned short* Bb = Bs[slot];
        bf16x8 af[8], bfr[4];
        #pragma unroll
        for (int i = 0; i < 8; ++i)
            af[i] = *(const bf16x8*)&Ab[(wm * 128 + i * 16 + l16) * BK + swz];
        #pragma unroll
        for (int j = 0; j < 4; ++j)
            bfr[j] = *(const bf16x8*)&Bb[(wn * 64 + j * 16 + l16) * BK + swz];
        #pragma unroll
        for (int i = 0; i < 8; ++i)
            #pragma unroll
            for (int j = 0; j < 4; ++j)
                acc[i][j] = __builtin_amdgcn_mfma_f32_16x16x32_bf16(
                    af[i], bfr[j], acc[i][j], 0, 0, 0);

        // counted drain: ensure tile kt+1 landed; keep kt+2/kt+3 in flight
        if (kt + 3 < NT) {
            asm volatile("s_waitcnt vmcnt(8)" ::: "memory");
        } else if (kt + 2 < NT) {
            asm volatile("s_waitcnt vmcnt(4)" ::: "memory");
        } else if (kt + 1 < NT) {
            asm volatile("s_waitcnt vmcnt(0)" ::: "memory");
        }
        __builtin_amdgcn_sched_barrier(0);
        __builtin_amdgcn_s_barrier();
    }

    // epilogue: bias + rank-8 lora dot, fp32 store
    float ufr[4][8];
    float bs[4];
    int gcol[4];
    #pragma unroll
    for (int j = 0; j < 4; ++j) {
        int col = n0 + wn * 64 + j * 16 + l16;
        gcol[j] = col;
        const float4* Ur = (const float4*)(U + (size_t)col * 8);
        float4 u0 = Ur[0], u1 = Ur[1];
        ufr[j][0] = u0.x; ufr[j][1] = u0.y; ufr[j][2] = u0.z; ufr[j][3] = u0.w;
        ufr[j][4] = u1.x; ufr[j][5] = u1.y; ufr[j][6] = u1.z; ufr[j][7] = u1.w;
        bs[j] = bias[col];
    }
    #pragma unroll
    for (int i = 0; i < 8; ++i) {
        #pragma unroll
        for (int r = 0; r < 4; ++r) {
            int grow = m0 + wm * 128 + i * 16 + quad * 4 + r;
            const float4* hr = (const float4*)(h + (size_t)grow * 8);
            float4 h0 = hr[0], h1 = hr[1];
            float hv[8] = {h0.x, h0.y, h0.z, h0.w, h1.x, h1.y, h1.z, h1.w};
            #pragma unroll
            for (int j = 0; j < 4; ++j) {
                float v = acc[i][j][r] + bs[j];
                #pragma unroll
                for (int q = 0; q < 8; ++q) v += hv[q] * ufr[j][q];
                C[(size_t)grow * N + gcol[j]] = v;
            }
        }
    }
}

extern "C" void kernel_launch(void* const* d_in, const int* in_sizes, int n_in,
                              void* d_out, int out_size, void* d_ws, size_t ws_size,
                              hipStream_t stream) {
    const float* x     = (const float*)d_in[0];
    const float* codes = (const float*)d_in[1];
    const float* W     = (const float*)d_in[2];
    const float* b     = (const float*)d_in[3];
    const float* V     = (const float*)d_in[4];
    const float* U     = (const float*)d_in[5];
    float* out = (float*)d_out;

    const int N = in_sizes[3];                 // D_OUT = 4096
    const int K = in_sizes[2] / N;             // D_IN  = 4096
    const int M = in_sizes[0] / K;             // B*S   = 16384

    char* ws = (char*)d_ws;
    unsigned short* xb = (unsigned short*)ws;                       // M*K bf16
    unsigned short* Wb = (unsigned short*)(ws + (size_t)M * K * 2); // N*K bf16
    float* h = (float*)(ws + (size_t)M * K * 2 + (size_t)N * K * 2);// M*8 fp32

    prep_x<<<M / PREP_ROWS, 256, 0, stream>>>(x, codes, V, xb, h, K);
    long n4 = (long)N * K / 4;
    cast_w<<<(int)((n4 + 255) / 256), 256, 0, stream>>>(W, Wb, n4);
    dim3 grid(N / BN, M / BM);
    gemm_bt<<<grid, 512, 0, stream>>>(xb, Wb, b, h, U, out, M, N, K);
}